// Round 5
// baseline (643.423 us; speedup 1.0000x reference)
//
#include <hip/hip_runtime.h>
#include <hip/hip_bf16.h>
#include <stdint.h>

#define IN_DIM 256
#define HID 16
#define OUTD 10
#define BKT_SHIFT 8            // 256 nodes per scan block
#define BKT_W 256

typedef short v8s __attribute__((ext_vector_type(8)));
typedef float v4f __attribute__((ext_vector_type(4)));

__device__ __forceinline__ float bf2f(unsigned short u) {
    return __uint_as_float(((unsigned int)u) << 16);
}
__device__ __forceinline__ unsigned short f2bf(float f) {
    unsigned int u = __float_as_uint(f);
    unsigned int lsb = (u >> 16) & 1u;
    u += 0x7fffu + lsb;  // round-to-nearest-even
    return (unsigned short)(u >> 16);
}

__device__ __forceinline__ int load_dst(const void* ei, int n_edges, int e, int is64) {
    return is64 ? (int)((const long long*)ei)[(size_t)n_edges + e]
                : ((const int*)ei)[(size_t)n_edges + e];
}
__device__ __forceinline__ int load_src(const void* ei, int n_edges, int e, int is64) {
    return is64 ? (int)((const long long*)ei)[e] : ((const int*)ei)[e];
}

// ---------------- setup + w1prep fused --------------------------------------
// Blocks 0..15: build the bf16 hi/lo split of W1 in MFMA-fragment layout
//   (each block locally detects wf32 from the first 256 W1 values -> no
//   dependency on flags). Block 16: dtype/is64 flag detect.
// All blocks: grid-stride zero of deg[n_nodes].
__global__ void setup_w1_kernel(const void* __restrict__ x,
                                const void* __restrict__ W1,
                                const void* __restrict__ ei,
                                int n_nodes, int* __restrict__ flags,
                                int* __restrict__ deg,
                                unsigned short* __restrict__ W1split) {
    int b = blockIdx.x, t = threadIdx.x;
    int gid = b * blockDim.x + t;
    for (int i = gid; i < n_nodes; i += gridDim.x * blockDim.x) deg[i] = 0;

    if (b == 16) {
        if (t < 64) {
            const unsigned short* xs = (const unsigned short*)x;
            const unsigned short* ws = (const unsigned short*)W1;
            bool badx = false, badw = false;
#pragma unroll
            for (int q = 0; q < 4; ++q) {
                float vx = bf2f(xs[t + 64 * q]);
                float vw = bf2f(ws[t + 64 * q]);
                if (!(vx > -1e4f && vx < 1e4f)) badx = true;
                if (!(vw > -1e4f && vw < 1e4f)) badw = true;
            }
            const unsigned long long* e64 = (const unsigned long long*)ei;
            bool big = false;
#pragma unroll
            for (int q = 0; q < 2; ++q)
                if (e64[t + 64 * q] >= (unsigned long long)n_nodes) big = true;
            int xf32 = __any(badx) ? 1 : 0;
            int wf32 = __any(badw) ? 1 : 0;
            int is64 = __any(big) ? 0 : 1;
            if (t == 0) { flags[0] = is64; flags[1] = xf32; flags[2] = wf32; }
        }
        return;
    }

    // local wf32 detect (first 256 bf16-interpreted values of W1)
    __shared__ int swf32;
    if (t == 0) swf32 = 0;
    __syncthreads();
    {
        float vw = bf2f(((const unsigned short*)W1)[t]);
        if (!(vw > -1e4f && vw < 1e4f)) swf32 = 1;   // benign race, same value
    }
    __syncthreads();
    const int wf32 = swf32;

    int i = b * 256 + t;                       // 0..4095 (i = k*16 + n)
    float w = wf32 ? ((const float*)W1)[i]
                   : bf2f(((const unsigned short*)W1)[i]);
    unsigned short hi = f2bf(w);
    unsigned short lo = f2bf(w - bf2f(hi));
    int k = i >> 4, n = i & 15;
    int kk = k >> 5, qd = (k >> 3) & 3, j = k & 7;
    int idx = ((kk * 4 + qd) * 16 + n) * 8 + j;  // = (kk*64 + lane)*8 + j
    W1split[idx] = hi;
    W1split[4096 + idx] = lo;
}

// ---------------- fat kernel: gemm1 (blocks < g_gemm) + node-degree hist ----
// gemm1: m1 = bf16(x @ W1), LDS-free streaming (W fragments from the w1prep
// split table, coalesced 16B loads, L1-resident). hist: distributed global
// atomics into deg[n_nodes] (400KB, L2-resident). Independent work -> the
// BW/atomic-bound hist overlaps the latency-bound GEMM waves.
__global__ __launch_bounds__(256, 4) void gemm1_hist_kernel(
        const void* __restrict__ xp_,
        const unsigned short* __restrict__ W1split,
        unsigned short* __restrict__ m1,
        const void* __restrict__ ei,
        int* __restrict__ deg,
        int n_nodes, int n_edges,
        const int* __restrict__ flags, int g_gemm) {
    int t = threadIdx.x;
    if ((int)blockIdx.x >= g_gemm) {
        // ---------- histogram role ----------
        int is64 = flags[0];
        int vbid = blockIdx.x - g_gemm;
        int stride = (gridDim.x - g_gemm) * 256;
        for (int e = vbid * 256 + t; e < n_edges; e += stride) {
            int d = load_dst(ei, n_edges, e, is64);
            atomicAdd(&deg[d], 1);
        }
        return;
    }
    // ---------- gemm1 role ----------
    const int xf32 = flags[1];
    int lane = t & 63;
    int wave = t >> 6;
    int col  = lane & 15;
    int quad = lane >> 4;
    int n_tiles = (n_nodes + 15) >> 4;
    const unsigned short* Whi = W1split;
    const unsigned short* Wlo = W1split + 4096;

    if (!xf32) {
        const unsigned short* x = (const unsigned short*)xp_;
        for (int tile = blockIdx.x * 4 + wave; tile < n_tiles; tile += g_gemm * 4) {
            int row = tile * 16 + col;
            int r = row < n_nodes ? row : n_nodes - 1;
            const unsigned short* xp = x + (size_t)r * IN_DIM + quad * 8;
            v8s a[8];
#pragma unroll
            for (int kk = 0; kk < 8; ++kk)
                a[kk] = *(const v8s*)(xp + kk * 32);
            v4f acc1 = {0.f, 0.f, 0.f, 0.f};
            v4f acc2 = {0.f, 0.f, 0.f, 0.f};
#pragma unroll
            for (int kk = 0; kk < 8; ++kk) {
                v8s bh = *(const v8s*)&Whi[(kk * 64 + lane) * 8];
                v8s bl = *(const v8s*)&Wlo[(kk * 64 + lane) * 8];
                acc1 = __builtin_amdgcn_mfma_f32_16x16x32_bf16(a[kk], bh, acc1, 0, 0, 0);
                acc2 = __builtin_amdgcn_mfma_f32_16x16x32_bf16(a[kk], bl, acc2, 0, 0, 0);
            }
#pragma unroll
            for (int rg = 0; rg < 4; ++rg) {
                int node = tile * 16 + quad * 4 + rg;
                if (node < n_nodes)
                    m1[(size_t)node * HID + col] = f2bf(acc1[rg] + acc2[rg]);
            }
        }
    } else {
        const float* x = (const float*)xp_;
        for (int tile = blockIdx.x * 4 + wave; tile < n_tiles; tile += g_gemm * 4) {
            int row = tile * 16 + col;
            int r = row < n_nodes ? row : n_nodes - 1;
            const float* xp = x + (size_t)r * IN_DIM + quad * 8;
            float4 u[16];
#pragma unroll
            for (int kk = 0; kk < 8; ++kk) {
                u[2 * kk]     = *(const float4*)(xp + kk * 32);
                u[2 * kk + 1] = *(const float4*)(xp + kk * 32 + 4);
            }
            v4f acc1 = {0.f, 0.f, 0.f, 0.f};   // ahi*bh chain
            v4f acc2 = {0.f, 0.f, 0.f, 0.f};   // ahi*bl + alo*bh chain
#pragma unroll
            for (int kk = 0; kk < 8; ++kk) {
                float uv[8] = {u[2 * kk].x,     u[2 * kk].y,
                               u[2 * kk].z,     u[2 * kk].w,
                               u[2 * kk + 1].x, u[2 * kk + 1].y,
                               u[2 * kk + 1].z, u[2 * kk + 1].w};
                v8s ahi, alo;
#pragma unroll
                for (int j = 0; j < 8; ++j) {
                    unsigned short hi = f2bf(uv[j]);
                    unsigned short lo = f2bf(uv[j] - bf2f(hi));
                    ahi[j] = (short)hi; alo[j] = (short)lo;
                }
                v8s bh = *(const v8s*)&Whi[(kk * 64 + lane) * 8];
                v8s bl = *(const v8s*)&Wlo[(kk * 64 + lane) * 8];
                acc1 = __builtin_amdgcn_mfma_f32_16x16x32_bf16(ahi, bh, acc1, 0, 0, 0);
                acc2 = __builtin_amdgcn_mfma_f32_16x16x32_bf16(ahi, bl, acc2, 0, 0, 0);
                acc2 = __builtin_amdgcn_mfma_f32_16x16x32_bf16(alo, bh, acc2, 0, 0, 0);
            }
#pragma unroll
            for (int rg = 0; rg < 4; ++rg) {
                int node = tile * 16 + quad * 4 + rg;
                if (node < n_nodes)
                    m1[(size_t)node * HID + col] = f2bf(acc1[rg] + acc2[rg]);
            }
        }
    }
}

// ---------------- scanA: per-256-node block sums of deg ---------------------
__global__ void scanA_kernel(const int* __restrict__ deg, int n_nodes,
                             int* __restrict__ bucket_cnt) {
    __shared__ int red[256];
    int b = blockIdx.x, t = threadIdx.x;
    int n = b * 256 + t;
    red[t] = (n < n_nodes) ? deg[n] : 0;
    __syncthreads();
    for (int o = 128; o > 0; o >>= 1) {
        if (t < o) red[t] += red[t + o];
        __syncthreads();
    }
    if (t == 0) bucket_cnt[b] = red[0];
}

// ---------------- bscan: exclusive scan over K block sums (1 block) ---------
__global__ void bscan_kernel(const int* __restrict__ bucket_cnt, int K,
                             int* __restrict__ bucket_off,
                             int* __restrict__ row_off, int n_nodes, int n_edges) {
    __shared__ int ts[256];
    int t = threadIdx.x;
    const int KP = (K + 255) / 256;   // <= 8
    int base = t * KP;
    int local[8];
    int s = 0;
    for (int q = 0; q < KP; ++q) {
        int idx = base + q;
        int v = (idx < K) ? bucket_cnt[idx] : 0;
        local[q] = v; s += v;
    }
    ts[t] = s;
    __syncthreads();
    for (int off = 1; off < 256; off <<= 1) {
        int v = (t >= off) ? ts[t - off] : 0;
        __syncthreads();
        ts[t] += v;
        __syncthreads();
    }
    int ex = ts[t] - s;
    for (int q = 0; q < KP; ++q) {
        int idx = base + q;
        if (idx < K) bucket_off[idx] = ex;
        ex += local[q];
    }
    if (t == 255) bucket_off[K] = ex;
    if (t == 0) row_off[n_nodes] = n_edges;
}

// ---------------- scanC: per-node exclusive scan -> row_off, cur ------------
__global__ void scanC_kernel(const int* __restrict__ deg,
                             const int* __restrict__ bucket_off,
                             int* __restrict__ row_off, int* __restrict__ cur,
                             int n_nodes) {
    __shared__ int ts[256];
    int b = blockIdx.x, t = threadIdx.x;
    int n = b * 256 + t;
    int d = (n < n_nodes) ? deg[n] : 0;
    ts[t] = d;
    __syncthreads();
    for (int off = 1; off < 256; off <<= 1) {
        int v = (t >= off) ? ts[t - off] : 0;
        __syncthreads();
        ts[t] += v;
        __syncthreads();
    }
    int ex = bucket_off[b] + ts[t] - d;
    if (n < n_nodes) { row_off[n] = ex; cur[n] = ex; }
}

// ---------------- scatter: csr_src[atomicAdd(cur[dst])] = src ---------------
// 4 edges/thread, index loads issued before the atomic/store chain (MLP).
__global__ __launch_bounds__(256) void scatter_kernel(
        const void* __restrict__ ei, int n_edges,
        int* __restrict__ cur, int* __restrict__ csr_src,
        const int* __restrict__ flags) {
    int is64 = flags[0];
    int base = blockIdx.x * 1024;
    int t = threadIdx.x;
    int d[4], s[4];
#pragma unroll
    for (int r = 0; r < 4; ++r) {
        int e = base + r * 256 + t;
        d[r] = (e < n_edges) ? load_dst(ei, n_edges, e, is64) : -1;
        s[r] = (e < n_edges) ? load_src(ei, n_edges, e, is64) : 0;
    }
#pragma unroll
    for (int r = 0; r < 4; ++r) {
        if (d[r] >= 0) {
            int pos = atomicAdd(&cur[d[r]], 1);
            csr_src[pos] = s[r];
        }
    }
}

// ---------------- gather-sum core: 4 lanes/node, bf16 rows, 16-deep MLP -----
__device__ __forceinline__ v4f gather_bf16(const unsigned short* __restrict__ src,
                                           const int* __restrict__ csr_src,
                                           int beg, int end, int q) {
    float a0 = 0.f, a1 = 0.f, a2 = 0.f, a3 = 0.f;
    int k = beg;
    for (; k + 16 <= end; k += 16) {
        uint2 v[16];
#pragma unroll
        for (int u = 0; u < 16; ++u) {
            int s = csr_src[k + u];
            v[u] = *(const uint2*)(src + (size_t)s * HID + q * 4);
        }
#pragma unroll
        for (int u = 0; u < 16; ++u) {
            a0 += bf2f((unsigned short)(v[u].x));
            a1 += bf2f((unsigned short)(v[u].x >> 16));
            a2 += bf2f((unsigned short)(v[u].y));
            a3 += bf2f((unsigned short)(v[u].y >> 16));
        }
    }
    for (; k + 4 <= end; k += 4) {
        uint2 v[4];
#pragma unroll
        for (int u = 0; u < 4; ++u) {
            int s = csr_src[k + u];
            v[u] = *(const uint2*)(src + (size_t)s * HID + q * 4);
        }
#pragma unroll
        for (int u = 0; u < 4; ++u) {
            a0 += bf2f((unsigned short)(v[u].x));
            a1 += bf2f((unsigned short)(v[u].x >> 16));
            a2 += bf2f((unsigned short)(v[u].y));
            a3 += bf2f((unsigned short)(v[u].y >> 16));
        }
    }
    for (; k < end; ++k) {
        int s = csr_src[k];
        uint2 v = *(const uint2*)(src + (size_t)s * HID + q * 4);
        a0 += bf2f((unsigned short)(v.x));
        a1 += bf2f((unsigned short)(v.x >> 16));
        a2 += bf2f((unsigned short)(v.y));
        a3 += bf2f((unsigned short)(v.y >> 16));
    }
    v4f r = {a0, a1, a2, a3};
    return r;
}

// ---------------- agg1: h = bf16(relu(A . m1 + b1)) -------------------------
__global__ void agg1_kernel(const unsigned short* __restrict__ m1,
                            const int* __restrict__ row_off,
                            const int* __restrict__ csr_src,
                            const void* __restrict__ b1p,
                            unsigned short* __restrict__ h, int n_nodes,
                            const int* __restrict__ flags) {
    int t = blockIdx.x * blockDim.x + threadIdx.x;
    int node = t >> 2;
    if (node >= n_nodes) return;
    int q = t & 3;
    const int wf32 = flags[2];
    v4f a = gather_bf16(m1, csr_src, row_off[node], row_off[node + 1], q);
    float b0, b1v, b2v, b3;
    if (wf32) {
        const float* b = (const float*)b1p + q * 4;
        b0 = b[0]; b1v = b[1]; b2v = b[2]; b3 = b[3];
    } else {
        const unsigned short* b = (const unsigned short*)b1p + q * 4;
        b0 = bf2f(b[0]); b1v = bf2f(b[1]); b2v = bf2f(b[2]); b3 = bf2f(b[3]);
    }
    float r0 = fmaxf(a[0] + b0, 0.f);
    float r1 = fmaxf(a[1] + b1v, 0.f);
    float r2 = fmaxf(a[2] + b2v, 0.f);
    float r3 = fmaxf(a[3] + b3, 0.f);
    uint2 packed;
    packed.x = (unsigned int)f2bf(r0) | ((unsigned int)f2bf(r1) << 16);
    packed.y = (unsigned int)f2bf(r2) | ((unsigned int)f2bf(r3) << 16);
    *(uint2*)(h + (size_t)node * HID + q * 4) = packed;
}

// ---------------- agg2 + out fused: out = (A . h) @ W2 + b2 -----------------
__global__ void agg2_out_kernel(const unsigned short* __restrict__ h,
                                const int* __restrict__ row_off,
                                const int* __restrict__ csr_src,
                                const void* __restrict__ W2p,
                                const void* __restrict__ b2p,
                                void* __restrict__ out, int n_nodes,
                                const int* __restrict__ flags) {
    __shared__ float Ws[HID * OUTD];
    __shared__ float bs[OUTD];
    const int xf32 = flags[1], wf32 = flags[2];
    if (threadIdx.x < HID * OUTD)
        Ws[threadIdx.x] = wf32 ? ((const float*)W2p)[threadIdx.x]
                               : bf2f(((const unsigned short*)W2p)[threadIdx.x]);
    if (threadIdx.x < OUTD)
        bs[threadIdx.x] = wf32 ? ((const float*)b2p)[threadIdx.x]
                               : bf2f(((const unsigned short*)b2p)[threadIdx.x]);
    __syncthreads();

    int t = blockIdx.x * blockDim.x + threadIdx.x;
    int node = t >> 2;
    if (node >= n_nodes) return;
    int q = t & 3;
    v4f a = gather_bf16(h, csr_src, row_off[node], row_off[node + 1], q);

    float o[OUTD];
#pragma unroll
    for (int od = 0; od < OUTD; ++od) {
        float s = 0.f;
#pragma unroll
        for (int j = 0; j < 4; ++j)
            s = fmaf(a[j], Ws[(q * 4 + j) * OUTD + od], s);
        o[od] = s;
    }
#pragma unroll
    for (int od = 0; od < OUTD; ++od) {
        o[od] += __shfl_xor(o[od], 1);
        o[od] += __shfl_xor(o[od], 2);
        o[od] += bs[od];
    }

    if (xf32) {
        float2* po = (float2*)((float*)out + (size_t)node * OUTD);
        if (q == 0) {
            po[0] = make_float2(o[0], o[1]);
            po[1] = make_float2(o[2], o[3]);
        } else if (q == 1) {
            po[2] = make_float2(o[4], o[5]);
            po[3] = make_float2(o[6], o[7]);
        } else if (q == 2) {
            po[4] = make_float2(o[8], o[9]);
        }
    } else {
        unsigned int* po = (unsigned int*)((unsigned short*)out + (size_t)node * OUTD);
        if (q == 0) {
            po[0] = (unsigned int)f2bf(o[0]) | ((unsigned int)f2bf(o[1]) << 16);
            po[1] = (unsigned int)f2bf(o[2]) | ((unsigned int)f2bf(o[3]) << 16);
        } else if (q == 1) {
            po[2] = (unsigned int)f2bf(o[4]) | ((unsigned int)f2bf(o[5]) << 16);
            po[3] = (unsigned int)f2bf(o[6]) | ((unsigned int)f2bf(o[7]) << 16);
        } else if (q == 2) {
            po[4] = (unsigned int)f2bf(o[8]) | ((unsigned int)f2bf(o[9]) << 16);
        }
    }
}

// ---------------- Sentinel: ws_size too small -------------------------------
__global__ void sentinel_kernel(float* __restrict__ out) {
    if (blockIdx.x == 0 && threadIdx.x < 16) out[threadIdx.x] = 123456.0f;
}

extern "C" void kernel_launch(void* const* d_in, const int* in_sizes, int n_in,
                              void* d_out, int out_size, void* d_ws, size_t ws_size,
                              hipStream_t stream) {
    const void* x  = d_in[0];
    const void* ei = d_in[1];
    const void* W1 = d_in[2];
    const void* b1 = d_in[3];
    const void* W2 = d_in[4];
    const void* b2 = d_in[5];

    const int n_nodes = in_sizes[0] / IN_DIM;        // 100000
    const int n_edges = in_sizes[1] / 2;             // 3200000
    const int K = (n_nodes + BKT_W - 1) / BKT_W;     // 391 scan blocks

    // Workspace layout (256B-aligned):
    // [flags | w1split | deg | cur | bucket_cnt | bucket_off | row_off |
    //  csr_src | m1(bf16) | h(bf16)]
    char* p = (char*)d_ws;
    auto align = [](size_t v) { return (v + 255) & ~(size_t)255; };
    size_t off = 0;
    int* flags      = (int*)(p + off); off = align(off + 256);
    unsigned short* w1split = (unsigned short*)(p + off); off = align(off + 8192 * 2);
    int* deg        = (int*)(p + off); off = align(off + (size_t)n_nodes * 4);
    int* cur        = (int*)(p + off); off = align(off + (size_t)n_nodes * 4);
    int* bucket_cnt = (int*)(p + off); off = align(off + (size_t)K * 4);
    int* bucket_off = (int*)(p + off); off = align(off + ((size_t)K + 1) * 4);
    int* row_off    = (int*)(p + off); off = align(off + ((size_t)n_nodes + 1) * 4);
    int* csr_src    = (int*)(p + off); off = align(off + (size_t)n_edges * 4);
    unsigned short* m1 = (unsigned short*)(p + off); off = align(off + (size_t)n_nodes * HID * 2);
    unsigned short* h  = (unsigned short*)(p + off); off = align(off + (size_t)n_nodes * HID * 2);

    if (ws_size < off) {
        sentinel_kernel<<<1, 64, 0, stream>>>((float*)d_out);
        return;
    }

    const int n_tiles16 = (n_nodes + 15) >> 4;        // 6250
    const int g_gemm = (n_tiles16 + 3) / 4;           // 1563 (1 tile/wave)
    const int g_hist = 1024;

    // 1. flags + W1 split + deg zero
    setup_w1_kernel<<<17, 256, 0, stream>>>(x, W1, ei, n_nodes, flags, deg, w1split);

    // 2. fat: gemm1 (m1) overlapped with per-node degree histogram
    gemm1_hist_kernel<<<g_gemm + g_hist, 256, 0, stream>>>(
        x, w1split, m1, ei, deg, n_nodes, n_edges, flags, g_gemm);

    // 3-5. hierarchical scan: deg -> row_off, cur
    scanA_kernel<<<K, 256, 0, stream>>>(deg, n_nodes, bucket_cnt);
    bscan_kernel<<<1, 256, 0, stream>>>(bucket_cnt, K, bucket_off,
                                        row_off, n_nodes, n_edges);
    scanC_kernel<<<K, 256, 0, stream>>>(deg, bucket_off, row_off, cur, n_nodes);

    // 6. direct scatter CSR build
    scatter_kernel<<<(n_edges + 1023) / 1024, 256, 0, stream>>>(
        ei, n_edges, cur, csr_src, flags);

    // 7. layer 1 aggregation
    {
        long long threads = (long long)n_nodes * 4;
        agg1_kernel<<<(int)((threads + 255) / 256), 256, 0, stream>>>(
            m1, row_off, csr_src, b1, h, n_nodes, flags);
    }

    // 8. layer 2 aggregation + output GEMM fused
    {
        long long threads = (long long)n_nodes * 4;
        agg2_out_kernel<<<(int)((threads + 255) / 256), 256, 0, stream>>>(
            h, row_off, csr_src, W2, b2, d_out, n_nodes, flags);
    }
}

// Round 6
// 348.912 us; speedup vs baseline: 1.8441x; 1.8441x over previous
//
#include <hip/hip_runtime.h>
#include <hip/hip_bf16.h>
#include <stdint.h>

#define IN_DIM 256
#define HID 16
#define OUTD 10
#define BKT_SHIFT 8            // 256 nodes per bucket
#define BKT_W 256
#define PART_CH 2048           // edges per partition block
#define EPT 8                  // edges per thread in part (PART_CH/256)

typedef short v8s __attribute__((ext_vector_type(8)));
typedef float v4f __attribute__((ext_vector_type(4)));

__device__ __forceinline__ float bf2f(unsigned short u) {
    return __uint_as_float(((unsigned int)u) << 16);
}
__device__ __forceinline__ unsigned short f2bf(float f) {
    unsigned int u = __float_as_uint(f);
    unsigned int lsb = (u >> 16) & 1u;
    u += 0x7fffu + lsb;  // round-to-nearest-even
    return (unsigned short)(u >> 16);
}

__device__ __forceinline__ int load_dst(const void* ei, int n_edges, int e, int is64) {
    return is64 ? (int)((const long long*)ei)[(size_t)n_edges + e]
                : ((const int*)ei)[(size_t)n_edges + e];
}
__device__ __forceinline__ int load_src(const void* ei, int n_edges, int e, int is64) {
    return is64 ? (int)((const long long*)ei)[e] : ((const int*)ei)[e];
}

// ---------------- setup + w1prep fused --------------------------------------
// Block 16: dtype/is64 flag detect. Blocks 0..15: bf16 hi/lo split of W1 in
// MFMA-fragment layout (local wf32 detect -> no dependency on flags).
// All blocks: zero bucket_cnt.
__global__ void setup_w1_kernel(const void* __restrict__ x,
                                const void* __restrict__ W1,
                                const void* __restrict__ ei,
                                int n_nodes, int* __restrict__ flags,
                                int* __restrict__ bucket_cnt, int K,
                                unsigned short* __restrict__ W1split) {
    int b = blockIdx.x, t = threadIdx.x;
    int gid = b * blockDim.x + t;
    for (int i = gid; i < K; i += gridDim.x * blockDim.x) bucket_cnt[i] = 0;

    if (b == 16) {
        if (t < 64) {
            const unsigned short* xs = (const unsigned short*)x;
            const unsigned short* ws = (const unsigned short*)W1;
            bool badx = false, badw = false;
#pragma unroll
            for (int q = 0; q < 4; ++q) {
                float vx = bf2f(xs[t + 64 * q]);
                float vw = bf2f(ws[t + 64 * q]);
                if (!(vx > -1e4f && vx < 1e4f)) badx = true;
                if (!(vw > -1e4f && vw < 1e4f)) badw = true;
            }
            const unsigned long long* e64 = (const unsigned long long*)ei;
            bool big = false;
#pragma unroll
            for (int q = 0; q < 2; ++q)
                if (e64[t + 64 * q] >= (unsigned long long)n_nodes) big = true;
            int xf32 = __any(badx) ? 1 : 0;
            int wf32 = __any(badw) ? 1 : 0;
            int is64 = __any(big) ? 0 : 1;
            if (t == 0) { flags[0] = is64; flags[1] = xf32; flags[2] = wf32; }
        }
        return;
    }

    // local wf32 detect (first 256 bf16-interpreted values of W1)
    __shared__ int swf32;
    if (t == 0) swf32 = 0;
    __syncthreads();
    {
        float vw = bf2f(((const unsigned short*)W1)[t]);
        if (!(vw > -1e4f && vw < 1e4f)) swf32 = 1;   // benign race, same value
    }
    __syncthreads();
    const int wf32 = swf32;

    int i = b * 256 + t;                       // 0..4095 (i = k*16 + n)
    float w = wf32 ? ((const float*)W1)[i]
                   : bf2f(((const unsigned short*)W1)[i]);
    unsigned short hi = f2bf(w);
    unsigned short lo = f2bf(w - bf2f(hi));
    int k = i >> 4, n = i & 15;
    int kk = k >> 5, qd = (k >> 3) & 3, j = k & 7;
    int idx = ((kk * 4 + qd) * 16 + n) * 8 + j;  // = (kk*64 + lane)*8 + j
    W1split[idx] = hi;
    W1split[4096 + idx] = lo;
}

// ---------------- fat: gemm1 (blocks < g_gemm) + bucket histogram -----------
// gemm1: m1 = bf16(x @ W1), LDS-free streaming (W fragments from the split
// table: coalesced 16B loads, L1-resident; no barriers). hist: LDS-staged
// bucket histogram of dst (independent of gemm1) -> overlaps the
// latency-bound GEMM waves with the BW-bound edge read.
__global__ __launch_bounds__(256, 4) void gemm1_bhist_kernel(
        const void* __restrict__ xp_,
        const unsigned short* __restrict__ W1split,
        unsigned short* __restrict__ m1,
        const void* __restrict__ ei,
        int* __restrict__ bucket_cnt,
        int n_nodes, int n_edges, int K,
        const int* __restrict__ flags, int g_gemm) {
    __shared__ int lh[512];
    int t = threadIdx.x;
    if ((int)blockIdx.x >= g_gemm) {
        // ---------- histogram role ----------
        for (int i = t; i < 512; i += 256) lh[i] = 0;
        __syncthreads();
        int is64 = flags[0];
        int vbid = blockIdx.x - g_gemm;
        int stride = (gridDim.x - g_gemm) * 256;
        for (int e = vbid * 256 + t; e < n_edges; e += stride) {
            int d = load_dst(ei, n_edges, e, is64);
            atomicAdd(&lh[d >> BKT_SHIFT], 1);
        }
        __syncthreads();
        for (int i = t; i < K; i += 256)
            if (lh[i]) atomicAdd(&bucket_cnt[i], lh[i]);
        return;
    }
    // ---------- gemm1 role ----------
    const int xf32 = flags[1];
    int lane = t & 63;
    int wave = t >> 6;
    int col  = lane & 15;
    int quad = lane >> 4;
    int n_tiles = (n_nodes + 15) >> 4;
    const unsigned short* Whi = W1split;
    const unsigned short* Wlo = W1split + 4096;

    if (!xf32) {
        const unsigned short* x = (const unsigned short*)xp_;
        for (int tile = blockIdx.x * 4 + wave; tile < n_tiles; tile += g_gemm * 4) {
            int row = tile * 16 + col;
            int r = row < n_nodes ? row : n_nodes - 1;
            const unsigned short* xp = x + (size_t)r * IN_DIM + quad * 8;
            v8s a[8];
#pragma unroll
            for (int kk = 0; kk < 8; ++kk)
                a[kk] = *(const v8s*)(xp + kk * 32);
            v4f acc1 = {0.f, 0.f, 0.f, 0.f};
            v4f acc2 = {0.f, 0.f, 0.f, 0.f};
#pragma unroll
            for (int kk = 0; kk < 8; ++kk) {
                v8s bh = *(const v8s*)&Whi[(kk * 64 + lane) * 8];
                v8s bl = *(const v8s*)&Wlo[(kk * 64 + lane) * 8];
                acc1 = __builtin_amdgcn_mfma_f32_16x16x32_bf16(a[kk], bh, acc1, 0, 0, 0);
                acc2 = __builtin_amdgcn_mfma_f32_16x16x32_bf16(a[kk], bl, acc2, 0, 0, 0);
            }
#pragma unroll
            for (int rg = 0; rg < 4; ++rg) {
                int node = tile * 16 + quad * 4 + rg;
                if (node < n_nodes)
                    m1[(size_t)node * HID + col] = f2bf(acc1[rg] + acc2[rg]);
            }
        }
    } else {
        const float* x = (const float*)xp_;
        for (int tile = blockIdx.x * 4 + wave; tile < n_tiles; tile += g_gemm * 4) {
            int row = tile * 16 + col;
            int r = row < n_nodes ? row : n_nodes - 1;
            const float* xp = x + (size_t)r * IN_DIM + quad * 8;
            float4 u[16];
#pragma unroll
            for (int kk = 0; kk < 8; ++kk) {
                u[2 * kk]     = *(const float4*)(xp + kk * 32);
                u[2 * kk + 1] = *(const float4*)(xp + kk * 32 + 4);
            }
            v4f acc1 = {0.f, 0.f, 0.f, 0.f};   // ahi*bh chain
            v4f acc2 = {0.f, 0.f, 0.f, 0.f};   // ahi*bl + alo*bh chain
#pragma unroll
            for (int kk = 0; kk < 8; ++kk) {
                float uv[8] = {u[2 * kk].x,     u[2 * kk].y,
                               u[2 * kk].z,     u[2 * kk].w,
                               u[2 * kk + 1].x, u[2 * kk + 1].y,
                               u[2 * kk + 1].z, u[2 * kk + 1].w};
                v8s ahi, alo;
#pragma unroll
                for (int j = 0; j < 8; ++j) {
                    unsigned short hi = f2bf(uv[j]);
                    unsigned short lo = f2bf(uv[j] - bf2f(hi));
                    ahi[j] = (short)hi; alo[j] = (short)lo;
                }
                v8s bh = *(const v8s*)&Whi[(kk * 64 + lane) * 8];
                v8s bl = *(const v8s*)&Wlo[(kk * 64 + lane) * 8];
                acc1 = __builtin_amdgcn_mfma_f32_16x16x32_bf16(ahi, bh, acc1, 0, 0, 0);
                acc2 = __builtin_amdgcn_mfma_f32_16x16x32_bf16(ahi, bl, acc2, 0, 0, 0);
                acc2 = __builtin_amdgcn_mfma_f32_16x16x32_bf16(alo, bh, acc2, 0, 0, 0);
            }
#pragma unroll
            for (int rg = 0; rg < 4; ++rg) {
                int node = tile * 16 + quad * 4 + rg;
                if (node < n_nodes)
                    m1[(size_t)node * HID + col] = f2bf(acc1[rg] + acc2[rg]);
            }
        }
    }
}

// ---------------- bucket scan (1 block) -------------------------------------
__global__ void bscan_kernel(const int* __restrict__ bucket_cnt, int K,
                             int* __restrict__ bucket_off, int* __restrict__ bcur,
                             int* __restrict__ row_off, int n_nodes, int n_edges) {
    __shared__ int ts[256];
    int t = threadIdx.x;
    const int KP = (K + 255) / 256;   // <= 8
    int base = t * KP;
    int local[8];
    int s = 0;
    for (int q = 0; q < KP; ++q) {
        int idx = base + q;
        int v = (idx < K) ? bucket_cnt[idx] : 0;
        local[q] = v; s += v;
    }
    ts[t] = s;
    __syncthreads();
    for (int off = 1; off < 256; off <<= 1) {
        int v = (t >= off) ? ts[t - off] : 0;
        __syncthreads();
        ts[t] += v;
        __syncthreads();
    }
    int ex = ts[t] - s;
    for (int q = 0; q < KP; ++q) {
        int idx = base + q;
        if (idx < K) { bucket_off[idx] = ex; bcur[idx] = ex; }
        ex += local[q];
    }
    if (t == 255) bucket_off[K] = ex;
    if (t == 0) row_off[n_nodes] = n_edges;
}

// ---------------- partition: in-LDS counting sort + coalesced flush ---------
// pair = (src << 8) | (dst & 255): 4B packed; output sorted by bucket.
// PART_CH=2048 (EPT 8): halves the per-thread serial atomic chain and cuts
// LDS to ~17KB (8 blocks/CU vs 5 at 4096).
__global__ void part_kernel(const void* __restrict__ ei, int n_edges,
                            int* __restrict__ bcur, unsigned int* __restrict__ pairs,
                            const int* __restrict__ flags, int K) {
    __shared__ int lh[512];                  // counts, then placement cursor
    __shared__ int gdelta[512];              // gstart[b] - lstart[b]
    __shared__ int ts[256];
    __shared__ unsigned int spairs[PART_CH]; // 8 KiB
    __shared__ unsigned short sbkt[PART_CH]; // 4 KiB
    int begin = blockIdx.x * PART_CH;
    int is64 = flags[0];
    int t = threadIdx.x;
    lh[t] = 0; lh[t + 256] = 0;

    int dloc[EPT];
#pragma unroll
    for (int i = 0; i < EPT; ++i) {
        int e = begin + i * 256 + t;
        dloc[i] = (e < n_edges) ? load_dst(ei, n_edges, e, is64) : -1;
    }
    __syncthreads();
#pragma unroll
    for (int i = 0; i < EPT; ++i)
        if (dloc[i] >= 0) atomicAdd(&lh[dloc[i] >> BKT_SHIFT], 1);
    __syncthreads();

    // block scan over 512 bucket counts (thread t owns entries 2t, 2t+1)
    int c0 = lh[2 * t], c1 = lh[2 * t + 1];
    int s = c0 + c1;
    ts[t] = s;
    __syncthreads();
    for (int off = 1; off < 256; off <<= 1) {
        int v = (t >= off) ? ts[t - off] : 0;
        __syncthreads();
        ts[t] += v;
        __syncthreads();
    }
    int ex = ts[t] - s;
    // reserve global runs; cursor = local exclusive start
    if (c0 > 0) gdelta[2 * t]     = atomicAdd(&bcur[2 * t], c0) - ex;
    if (c1 > 0) gdelta[2 * t + 1] = atomicAdd(&bcur[2 * t + 1], c1) - (ex + c0);
    __syncthreads();   // everyone done reading lh counts before overwrite
    lh[2 * t] = ex; lh[2 * t + 1] = ex + c0;
    __syncthreads();

    // place into LDS, sorted by bucket
#pragma unroll
    for (int i = 0; i < EPT; ++i) {
        int e = begin + i * 256 + t;
        if (dloc[i] >= 0) {
            int srcv = load_src(ei, n_edges, e, is64);
            int b = dloc[i] >> BKT_SHIFT;
            int lpos = atomicAdd(&lh[b], 1);
            spairs[lpos] = ((unsigned)srcv << 8) | ((unsigned)dloc[i] & (BKT_W - 1));
            sbkt[lpos] = (unsigned short)b;
        }
    }
    __syncthreads();

    // coalesced flush: ascending j walks bucket runs contiguously
    int total = n_edges - begin; if (total > PART_CH) total = PART_CH;
    for (int j = t; j < total; j += 256)
        pairs[gdelta[sbkt[j]] + j] = spairs[j];
}

// ---------------- per-bucket CSR build (256-node buckets, 512 thr) ----------
__global__ void csr_kernel(const unsigned int* __restrict__ pairs,
                           const int* __restrict__ bucket_off,
                           int* __restrict__ row_off, int* __restrict__ csr_src,
                           int n_nodes) {
    __shared__ int deg[BKT_W];
    __shared__ int cur[BKT_W];
    __shared__ int ts[BKT_W];
    int blk = blockIdx.x;
    int nbase = blk << BKT_SHIFT;
    int NL = n_nodes - nbase; if (NL > BKT_W) NL = BKT_W;
    int beg = bucket_off[blk], end = bucket_off[blk + 1];
    int t = threadIdx.x;
    if (t < BKT_W) deg[t] = 0;
    __syncthreads();
    for (int k = beg + t; k < end; k += blockDim.x)
        atomicAdd(&deg[pairs[k] & (BKT_W - 1)], 1);
    __syncthreads();
    if (t < BKT_W) ts[t] = deg[t];
    __syncthreads();
    for (int off = 1; off < BKT_W; off <<= 1) {
        int v = 0;
        if (t < BKT_W && t >= off) v = ts[t - off];
        __syncthreads();
        if (t < BKT_W) ts[t] += v;
        __syncthreads();
    }
    if (t < BKT_W) {
        int ex = beg + ts[t] - deg[t];
        cur[t] = ex;
        if (t < NL) row_off[nbase + t] = ex;
    }
    __syncthreads();
    for (int k = beg + t; k < end; k += blockDim.x) {
        unsigned int p = pairs[k];
        int pos = atomicAdd(&cur[p & (BKT_W - 1)], 1);
        csr_src[pos] = (int)(p >> 8);
    }
}

// ---------------- gather-sum core: 4 lanes/node, bf16 rows, 16-deep MLP -----
__device__ __forceinline__ v4f gather_bf16(const unsigned short* __restrict__ src,
                                           const int* __restrict__ csr_src,
                                           int beg, int end, int q) {
    float a0 = 0.f, a1 = 0.f, a2 = 0.f, a3 = 0.f;
    int k = beg;
    for (; k + 16 <= end; k += 16) {
        uint2 v[16];
#pragma unroll
        for (int u = 0; u < 16; ++u) {
            int s = csr_src[k + u];
            v[u] = *(const uint2*)(src + (size_t)s * HID + q * 4);
        }
#pragma unroll
        for (int u = 0; u < 16; ++u) {
            a0 += bf2f((unsigned short)(v[u].x));
            a1 += bf2f((unsigned short)(v[u].x >> 16));
            a2 += bf2f((unsigned short)(v[u].y));
            a3 += bf2f((unsigned short)(v[u].y >> 16));
        }
    }
    for (; k + 4 <= end; k += 4) {
        uint2 v[4];
#pragma unroll
        for (int u = 0; u < 4; ++u) {
            int s = csr_src[k + u];
            v[u] = *(const uint2*)(src + (size_t)s * HID + q * 4);
        }
#pragma unroll
        for (int u = 0; u < 4; ++u) {
            a0 += bf2f((unsigned short)(v[u].x));
            a1 += bf2f((unsigned short)(v[u].x >> 16));
            a2 += bf2f((unsigned short)(v[u].y));
            a3 += bf2f((unsigned short)(v[u].y >> 16));
        }
    }
    for (; k < end; ++k) {
        int s = csr_src[k];
        uint2 v = *(const uint2*)(src + (size_t)s * HID + q * 4);
        a0 += bf2f((unsigned short)(v.x));
        a1 += bf2f((unsigned short)(v.x >> 16));
        a2 += bf2f((unsigned short)(v.y));
        a3 += bf2f((unsigned short)(v.y >> 16));
    }
    v4f r = {a0, a1, a2, a3};
    return r;
}

// ---------------- agg1: h = bf16(relu(A . m1 + b1)) -------------------------
__global__ void agg1_kernel(const unsigned short* __restrict__ m1,
                            const int* __restrict__ row_off,
                            const int* __restrict__ csr_src,
                            const void* __restrict__ b1p,
                            unsigned short* __restrict__ h, int n_nodes,
                            const int* __restrict__ flags) {
    int t = blockIdx.x * blockDim.x + threadIdx.x;
    int node = t >> 2;
    if (node >= n_nodes) return;
    int q = t & 3;
    const int wf32 = flags[2];
    v4f a = gather_bf16(m1, csr_src, row_off[node], row_off[node + 1], q);
    float b0, b1v, b2v, b3;
    if (wf32) {
        const float* b = (const float*)b1p + q * 4;
        b0 = b[0]; b1v = b[1]; b2v = b[2]; b3 = b[3];
    } else {
        const unsigned short* b = (const unsigned short*)b1p + q * 4;
        b0 = bf2f(b[0]); b1v = bf2f(b[1]); b2v = bf2f(b[2]); b3 = bf2f(b[3]);
    }
    float r0 = fmaxf(a[0] + b0, 0.f);
    float r1 = fmaxf(a[1] + b1v, 0.f);
    float r2 = fmaxf(a[2] + b2v, 0.f);
    float r3 = fmaxf(a[3] + b3, 0.f);
    uint2 packed;
    packed.x = (unsigned int)f2bf(r0) | ((unsigned int)f2bf(r1) << 16);
    packed.y = (unsigned int)f2bf(r2) | ((unsigned int)f2bf(r3) << 16);
    *(uint2*)(h + (size_t)node * HID + q * 4) = packed;
}

// ---------------- agg2 + out fused: out = (A . h) @ W2 + b2 -----------------
__global__ void agg2_out_kernel(const unsigned short* __restrict__ h,
                                const int* __restrict__ row_off,
                                const int* __restrict__ csr_src,
                                const void* __restrict__ W2p,
                                const void* __restrict__ b2p,
                                void* __restrict__ out, int n_nodes,
                                const int* __restrict__ flags) {
    __shared__ float Ws[HID * OUTD];
    __shared__ float bs[OUTD];
    const int xf32 = flags[1], wf32 = flags[2];
    if (threadIdx.x < HID * OUTD)
        Ws[threadIdx.x] = wf32 ? ((const float*)W2p)[threadIdx.x]
                               : bf2f(((const unsigned short*)W2p)[threadIdx.x]);
    if (threadIdx.x < OUTD)
        bs[threadIdx.x] = wf32 ? ((const float*)b2p)[threadIdx.x]
                               : bf2f(((const unsigned short*)b2p)[threadIdx.x]);
    __syncthreads();

    int t = blockIdx.x * blockDim.x + threadIdx.x;
    int node = t >> 2;
    if (node >= n_nodes) return;
    int q = t & 3;
    v4f a = gather_bf16(h, csr_src, row_off[node], row_off[node + 1], q);

    float o[OUTD];
#pragma unroll
    for (int od = 0; od < OUTD; ++od) {
        float s = 0.f;
#pragma unroll
        for (int j = 0; j < 4; ++j)
            s = fmaf(a[j], Ws[(q * 4 + j) * OUTD + od], s);
        o[od] = s;
    }
#pragma unroll
    for (int od = 0; od < OUTD; ++od) {
        o[od] += __shfl_xor(o[od], 1);
        o[od] += __shfl_xor(o[od], 2);
        o[od] += bs[od];
    }

    if (xf32) {
        float2* po = (float2*)((float*)out + (size_t)node * OUTD);
        if (q == 0) {
            po[0] = make_float2(o[0], o[1]);
            po[1] = make_float2(o[2], o[3]);
        } else if (q == 1) {
            po[2] = make_float2(o[4], o[5]);
            po[3] = make_float2(o[6], o[7]);
        } else if (q == 2) {
            po[4] = make_float2(o[8], o[9]);
        }
    } else {
        unsigned int* po = (unsigned int*)((unsigned short*)out + (size_t)node * OUTD);
        if (q == 0) {
            po[0] = (unsigned int)f2bf(o[0]) | ((unsigned int)f2bf(o[1]) << 16);
            po[1] = (unsigned int)f2bf(o[2]) | ((unsigned int)f2bf(o[3]) << 16);
        } else if (q == 1) {
            po[2] = (unsigned int)f2bf(o[4]) | ((unsigned int)f2bf(o[5]) << 16);
            po[3] = (unsigned int)f2bf(o[6]) | ((unsigned int)f2bf(o[7]) << 16);
        } else if (q == 2) {
            po[4] = (unsigned int)f2bf(o[8]) | ((unsigned int)f2bf(o[9]) << 16);
        }
    }
}

// ---------------- Sentinel: ws_size too small -------------------------------
__global__ void sentinel_kernel(float* __restrict__ out) {
    if (blockIdx.x == 0 && threadIdx.x < 16) out[threadIdx.x] = 123456.0f;
}

extern "C" void kernel_launch(void* const* d_in, const int* in_sizes, int n_in,
                              void* d_out, int out_size, void* d_ws, size_t ws_size,
                              hipStream_t stream) {
    const void* x  = d_in[0];
    const void* ei = d_in[1];
    const void* W1 = d_in[2];
    const void* b1 = d_in[3];
    const void* W2 = d_in[4];
    const void* b2 = d_in[5];

    const int n_nodes = in_sizes[0] / IN_DIM;        // 100000
    const int n_edges = in_sizes[1] / 2;             // 3200000
    const int K = (n_nodes + BKT_W - 1) / BKT_W;     // 391 buckets

    // Workspace layout (256B-aligned). gemm1 runs concurrently with bhist and
    // before part -> m1/h must NOT alias pairs.
    char* p = (char*)d_ws;
    auto align = [](size_t v) { return (v + 255) & ~(size_t)255; };
    size_t off = 0;
    int* flags      = (int*)(p + off); off = align(off + 256);
    unsigned short* w1split = (unsigned short*)(p + off); off = align(off + 8192 * 2);
    int* bucket_cnt = (int*)(p + off); off = align(off + (size_t)K * 4);
    int* bucket_off = (int*)(p + off); off = align(off + ((size_t)K + 1) * 4);
    int* bcur       = (int*)(p + off); off = align(off + (size_t)K * 4);
    int* row_off    = (int*)(p + off); off = align(off + ((size_t)n_nodes + 1) * 4);
    int* csr_src    = (int*)(p + off); off = align(off + (size_t)n_edges * 4);
    unsigned int* pairs = (unsigned int*)(p + off); off = align(off + (size_t)n_edges * 4);
    unsigned short* m1 = (unsigned short*)(p + off); off = align(off + (size_t)n_nodes * HID * 2);
    unsigned short* h  = (unsigned short*)(p + off); off = align(off + (size_t)n_nodes * HID * 2);

    if (ws_size < off) {
        sentinel_kernel<<<1, 64, 0, stream>>>((float*)d_out);
        return;
    }

    const int n_tiles16 = (n_nodes + 15) >> 4;        // 6250
    const int g_gemm = (n_tiles16 + 3) / 4;           // 1563 (1 tile/wave)
    const int g_hist = 512;

    // 1. flags + W1 split + bucket_cnt zero
    setup_w1_kernel<<<17, 256, 0, stream>>>(x, W1, ei, n_nodes, flags,
                                            bucket_cnt, K, w1split);

    // 2. fat: gemm1 (m1) overlapped with bucket histogram
    gemm1_bhist_kernel<<<g_gemm + g_hist, 256, 0, stream>>>(
        x, w1split, m1, ei, bucket_cnt, n_nodes, n_edges, K, flags, g_gemm);

    // 3. bucket scan
    bscan_kernel<<<1, 256, 0, stream>>>(bucket_cnt, K, bucket_off, bcur,
                                        row_off, n_nodes, n_edges);

    // 4. partition into bucket-sorted pairs
    part_kernel<<<(n_edges + PART_CH - 1) / PART_CH, 256, 0, stream>>>(
        ei, n_edges, bcur, pairs, flags, K);

    // 5. per-bucket CSR build
    csr_kernel<<<K, 512, 0, stream>>>(pairs, bucket_off, row_off, csr_src, n_nodes);

    // 6. layer 1 aggregation
    {
        long long threads = (long long)n_nodes * 4;
        agg1_kernel<<<(int)((threads + 255) / 256), 256, 0, stream>>>(
            m1, row_off, csr_src, b1, h, n_nodes, flags);
    }

    // 7. layer 2 aggregation + output GEMM fused
    {
        long long threads = (long long)n_nodes * 4;
        agg2_out_kernel<<<(int)((threads + 255) / 256), 256, 0, stream>>>(
            h, row_off, csr_src, W2, b2, d_out, n_nodes, flags);
    }
}

// Round 8
// 311.271 us; speedup vs baseline: 2.0671x; 1.1209x over previous
//
#include <hip/hip_runtime.h>
#include <hip/hip_bf16.h>
#include <stdint.h>

#define IN_DIM 256
#define HID 16
#define OUTD 10
#define BKT_SHIFT 8            // 256 nodes per bucket
#define BKT_W 256
#define PART_CH 4096           // edges per partition block (best measured)
#define EPT 16                 // edges per thread in part
#define G_HIST 512             // histogram blocks in K1
#define SSRC_CAP 8704          // LDS src-list capacity (mean 8192 + ~5 sigma)

typedef short v8s __attribute__((ext_vector_type(8)));
typedef float v4f __attribute__((ext_vector_type(4)));

__device__ __forceinline__ float bf2f(unsigned short u) {
    return __uint_as_float(((unsigned int)u) << 16);
}
__device__ __forceinline__ unsigned short f2bf(float f) {
    unsigned int u = __float_as_uint(f);
    unsigned int lsb = (u >> 16) & 1u;
    u += 0x7fffu + lsb;  // round-to-nearest-even
    return (unsigned short)(u >> 16);
}

__device__ __forceinline__ int load_dst(const void* ei, int n_edges, int e, int is64) {
    return is64 ? (int)((const long long*)ei)[(size_t)n_edges + e]
                : ((const int*)ei)[(size_t)n_edges + e];
}
__device__ __forceinline__ int load_src(const void* ei, int n_edges, int e, int is64) {
    return is64 ? (int)((const long long*)ei)[e] : ((const int*)ei)[e];
}

// ---------------- zero: bucket counters (plain kernel, no memset API) -------
__global__ void zero_kernel(int* __restrict__ bucket_cnt, int K) {
    for (int i = threadIdx.x; i < K; i += blockDim.x) bucket_cnt[i] = 0;
}

// ---------------- K1 fat: setup/flags/W1-split (17 blocks) + bhist ----------
// Blocks 0..15: bf16 hi/lo split of W1 in MFMA-fragment layout (local wf32
// detect). Block 16: global dtype/is64 flags. Blocks 17..: LDS-staged bucket
// histogram with local is64 detect (no flags dependency -> same launch).
__global__ void setup_bhist_kernel(const void* __restrict__ x,
                                   const void* __restrict__ W1,
                                   const void* __restrict__ ei,
                                   int n_nodes, int n_edges,
                                   int* __restrict__ flags,
                                   int* __restrict__ bucket_cnt, int K,
                                   unsigned short* __restrict__ W1split) {
    __shared__ int lh[512];
    __shared__ int sflag;
    int b = blockIdx.x, t = threadIdx.x;

    if (b < 16) {
        // ---- W1 split role (local wf32 detect over first 256 values) ----
        if (t == 0) sflag = 0;
        __syncthreads();
        {
            float vw = bf2f(((const unsigned short*)W1)[t]);
            if (!(vw > -1e4f && vw < 1e4f)) sflag = 1;   // benign same-value race
        }
        __syncthreads();
        const int wf32 = sflag;
        int i = b * 256 + t;                       // 0..4095 (i = k*16 + n)
        float w = wf32 ? ((const float*)W1)[i]
                       : bf2f(((const unsigned short*)W1)[i]);
        unsigned short hi = f2bf(w);
        unsigned short lo = f2bf(w - bf2f(hi));
        int k = i >> 4, n = i & 15;
        int kk = k >> 5, qd = (k >> 3) & 3, j = k & 7;
        int idx = ((kk * 4 + qd) * 16 + n) * 8 + j;  // = (kk*64 + lane)*8 + j
        W1split[idx] = hi;
        W1split[4096 + idx] = lo;
        return;
    }
    if (b == 16) {
        // ---- global flags role ----
        if (t < 64) {
            const unsigned short* xs = (const unsigned short*)x;
            const unsigned short* ws = (const unsigned short*)W1;
            bool badx = false, badw = false;
#pragma unroll
            for (int q = 0; q < 4; ++q) {
                float vx = bf2f(xs[t + 64 * q]);
                float vw = bf2f(ws[t + 64 * q]);
                if (!(vx > -1e4f && vx < 1e4f)) badx = true;
                if (!(vw > -1e4f && vw < 1e4f)) badw = true;
            }
            const unsigned long long* e64 = (const unsigned long long*)ei;
            bool big = false;
#pragma unroll
            for (int q = 0; q < 2; ++q)
                if (e64[t + 64 * q] >= (unsigned long long)n_nodes) big = true;
            int xf32 = __any(badx) ? 1 : 0;
            int wf32 = __any(badw) ? 1 : 0;
            int is64 = __any(big) ? 0 : 1;
            if (t == 0) { flags[0] = is64; flags[1] = xf32; flags[2] = wf32; }
        }
        return;
    }

    // ---- bhist role (local is64 detect over first 128 u64 reads) ----
    if (t == 0) sflag = 1;
    __syncthreads();
    {
        const unsigned long long* e64 = (const unsigned long long*)ei;
        if (t < 128 && e64[t] >= (unsigned long long)n_nodes) sflag = 0;
    }
    __syncthreads();
    const int is64 = sflag;
    for (int i = t; i < 512; i += 256) lh[i] = 0;
    __syncthreads();
    int vbid = b - 17;
    int stride = G_HIST * 256;
    for (int e = vbid * 256 + t; e < n_edges; e += stride) {
        int d = load_dst(ei, n_edges, e, is64);
        atomicAdd(&lh[d >> BKT_SHIFT], 1);
    }
    __syncthreads();
    for (int i = t; i < K; i += 256)
        if (lh[i]) atomicAdd(&bucket_cnt[i], lh[i]);
}

// ---------------- bucket scan (1 block) -------------------------------------
__global__ void bscan_kernel(const int* __restrict__ bucket_cnt, int K,
                             int* __restrict__ bucket_off, int* __restrict__ bcur,
                             int* __restrict__ row_off, int n_nodes, int n_edges) {
    __shared__ int ts[256];
    int t = threadIdx.x;
    const int KP = (K + 255) / 256;   // <= 8
    int base = t * KP;
    int local[8];
    int s = 0;
    for (int q = 0; q < KP; ++q) {
        int idx = base + q;
        int v = (idx < K) ? bucket_cnt[idx] : 0;
        local[q] = v; s += v;
    }
    ts[t] = s;
    __syncthreads();
    for (int off = 1; off < 256; off <<= 1) {
        int v = (t >= off) ? ts[t - off] : 0;
        __syncthreads();
        ts[t] += v;
        __syncthreads();
    }
    int ex = ts[t] - s;
    for (int q = 0; q < KP; ++q) {
        int idx = base + q;
        if (idx < K) { bucket_off[idx] = ex; bcur[idx] = ex; }
        ex += local[q];
    }
    if (t == 255) bucket_off[K] = ex;
    if (t == 0) row_off[n_nodes] = n_edges;
}

// ---------------- K2 fat: part (blocks < g_part) + gemm1 --------------------
// part: in-LDS counting sort into bucket-sorted pairs (proven PART_CH=4096).
// gemm1: m1 = bf16(x @ W1), LDS-free streaming. part is blockIdx-first so its
// long barrier-heavy blocks start immediately; gemm's short latency-bound
// blocks weave into remaining CU slots -> overlap instead of serial.
__global__ __launch_bounds__(256, 4) void part_gemm1_kernel(
        const void* __restrict__ ei, int n_edges,
        int* __restrict__ bcur, unsigned int* __restrict__ pairs,
        const void* __restrict__ xp_,
        const unsigned short* __restrict__ W1split,
        unsigned short* __restrict__ m1, int n_nodes,
        const int* __restrict__ flags, int K, int g_part) {
    __shared__ int lh[512];                  // counts, then placement cursor
    __shared__ int gdelta[512];              // gstart[b] - lstart[b]
    __shared__ int ts[256];
    __shared__ unsigned int spairs[PART_CH]; // 16 KiB
    __shared__ unsigned short sbkt[PART_CH]; // 8 KiB
    int t = threadIdx.x;

    if ((int)blockIdx.x < g_part) {
        // ---------- partition role ----------
        int begin = blockIdx.x * PART_CH;
        int is64 = flags[0];
        lh[t] = 0; lh[t + 256] = 0;

        int dloc[EPT];
#pragma unroll
        for (int i = 0; i < EPT; ++i) {
            int e = begin + i * 256 + t;
            dloc[i] = (e < n_edges) ? load_dst(ei, n_edges, e, is64) : -1;
        }
        __syncthreads();
#pragma unroll
        for (int i = 0; i < EPT; ++i)
            if (dloc[i] >= 0) atomicAdd(&lh[dloc[i] >> BKT_SHIFT], 1);
        __syncthreads();

        // block scan over 512 bucket counts (thread t owns entries 2t, 2t+1)
        int c0 = lh[2 * t], c1 = lh[2 * t + 1];
        int s = c0 + c1;
        ts[t] = s;
        __syncthreads();
        for (int off = 1; off < 256; off <<= 1) {
            int v = (t >= off) ? ts[t - off] : 0;
            __syncthreads();
            ts[t] += v;
            __syncthreads();
        }
        int ex = ts[t] - s;
        if (c0 > 0) gdelta[2 * t]     = atomicAdd(&bcur[2 * t], c0) - ex;
        if (c1 > 0) gdelta[2 * t + 1] = atomicAdd(&bcur[2 * t + 1], c1) - (ex + c0);
        __syncthreads();
        lh[2 * t] = ex; lh[2 * t + 1] = ex + c0;
        __syncthreads();

#pragma unroll
        for (int i = 0; i < EPT; ++i) {
            int e = begin + i * 256 + t;
            if (dloc[i] >= 0) {
                int srcv = load_src(ei, n_edges, e, is64);
                int bb = dloc[i] >> BKT_SHIFT;
                int lpos = atomicAdd(&lh[bb], 1);
                spairs[lpos] = ((unsigned)srcv << 8) | ((unsigned)dloc[i] & (BKT_W - 1));
                sbkt[lpos] = (unsigned short)bb;
            }
        }
        __syncthreads();

        int total = n_edges - begin; if (total > PART_CH) total = PART_CH;
        for (int j = t; j < total; j += 256)
            pairs[gdelta[sbkt[j]] + j] = spairs[j];
        return;
    }

    // ---------- gemm1 role ----------
    const int xf32 = flags[1];
    int vb = blockIdx.x - g_part;
    int g_gemm = gridDim.x - g_part;
    int lane = t & 63;
    int wave = t >> 6;
    int col  = lane & 15;
    int quad = lane >> 4;
    int n_tiles = (n_nodes + 15) >> 4;
    const unsigned short* Whi = W1split;
    const unsigned short* Wlo = W1split + 4096;

    if (!xf32) {
        const unsigned short* x = (const unsigned short*)xp_;
        for (int tile = vb * 4 + wave; tile < n_tiles; tile += g_gemm * 4) {
            int row = tile * 16 + col;
            int r = row < n_nodes ? row : n_nodes - 1;
            const unsigned short* xp = x + (size_t)r * IN_DIM + quad * 8;
            v8s a[8];
#pragma unroll
            for (int kk = 0; kk < 8; ++kk)
                a[kk] = *(const v8s*)(xp + kk * 32);
            v4f acc1 = {0.f, 0.f, 0.f, 0.f};
            v4f acc2 = {0.f, 0.f, 0.f, 0.f};
#pragma unroll
            for (int kk = 0; kk < 8; ++kk) {
                v8s bh = *(const v8s*)&Whi[(kk * 64 + lane) * 8];
                v8s bl = *(const v8s*)&Wlo[(kk * 64 + lane) * 8];
                acc1 = __builtin_amdgcn_mfma_f32_16x16x32_bf16(a[kk], bh, acc1, 0, 0, 0);
                acc2 = __builtin_amdgcn_mfma_f32_16x16x32_bf16(a[kk], bl, acc2, 0, 0, 0);
            }
#pragma unroll
            for (int rg = 0; rg < 4; ++rg) {
                int node = tile * 16 + quad * 4 + rg;
                if (node < n_nodes)
                    m1[(size_t)node * HID + col] = f2bf(acc1[rg] + acc2[rg]);
            }
        }
    } else {
        const float* x = (const float*)xp_;
        for (int tile = vb * 4 + wave; tile < n_tiles; tile += g_gemm * 4) {
            int row = tile * 16 + col;
            int r = row < n_nodes ? row : n_nodes - 1;
            const float* xp = x + (size_t)r * IN_DIM + quad * 8;
            float4 u[16];
#pragma unroll
            for (int kk = 0; kk < 8; ++kk) {
                u[2 * kk]     = *(const float4*)(xp + kk * 32);
                u[2 * kk + 1] = *(const float4*)(xp + kk * 32 + 4);
            }
            v4f acc1 = {0.f, 0.f, 0.f, 0.f};   // ahi*bh chain
            v4f acc2 = {0.f, 0.f, 0.f, 0.f};   // ahi*bl + alo*bh chain
#pragma unroll
            for (int kk = 0; kk < 8; ++kk) {
                float uv[8] = {u[2 * kk].x,     u[2 * kk].y,
                               u[2 * kk].z,     u[2 * kk].w,
                               u[2 * kk + 1].x, u[2 * kk + 1].y,
                               u[2 * kk + 1].z, u[2 * kk + 1].w};
                v8s ahi, alo;
#pragma unroll
                for (int j = 0; j < 8; ++j) {
                    unsigned short hi = f2bf(uv[j]);
                    unsigned short lo = f2bf(uv[j] - bf2f(hi));
                    ahi[j] = (short)hi; alo[j] = (short)lo;
                }
                v8s bh = *(const v8s*)&Whi[(kk * 64 + lane) * 8];
                v8s bl = *(const v8s*)&Wlo[(kk * 64 + lane) * 8];
                acc1 = __builtin_amdgcn_mfma_f32_16x16x32_bf16(ahi, bh, acc1, 0, 0, 0);
                acc2 = __builtin_amdgcn_mfma_f32_16x16x32_bf16(ahi, bl, acc2, 0, 0, 0);
                acc2 = __builtin_amdgcn_mfma_f32_16x16x32_bf16(alo, bh, acc2, 0, 0, 0);
            }
#pragma unroll
            for (int rg = 0; rg < 4; ++rg) {
                int node = tile * 16 + quad * 4 + rg;
                if (node < n_nodes)
                    m1[(size_t)node * HID + col] = f2bf(acc1[rg] + acc2[rg]);
            }
        }
    }
}

// ---------------- K3: csr build + agg1 fused (one block per bucket) ---------
// Builds the bucket's per-node CSR (writes row_off + csr_src for agg2) while
// keeping the sorted src list in LDS, then immediately aggregates
// h = bf16(relu(sum m1[src] + b1)) for its 256 nodes. Saves the csr_src
// re-read + row_off re-read + one launch vs separate csr/agg1.
__global__ __launch_bounds__(512) void csr_agg1_kernel(
        const unsigned int* __restrict__ pairs,
        const int* __restrict__ bucket_off,
        const unsigned short* __restrict__ m1,
        const void* __restrict__ b1p,
        int* __restrict__ row_off, int* __restrict__ csr_src,
        unsigned short* __restrict__ h,
        int n_nodes, const int* __restrict__ flags) {
    __shared__ unsigned int ssrc[SSRC_CAP];   // 34 KiB sorted src list
    __shared__ int deg[BKT_W];
    __shared__ int cur[BKT_W];
    __shared__ int ts[BKT_W];
    int blk = blockIdx.x;
    int nbase = blk << BKT_SHIFT;
    int NL = n_nodes - nbase; if (NL > BKT_W) NL = BKT_W;
    int beg = bucket_off[blk], end = bucket_off[blk + 1];
    int t = threadIdx.x;

    if (t < BKT_W) deg[t] = 0;
    __syncthreads();
    for (int k = beg + t; k < end; k += 512)
        atomicAdd(&deg[pairs[k] & (BKT_W - 1)], 1);
    __syncthreads();
    if (t < BKT_W) ts[t] = deg[t];
    __syncthreads();
    for (int off = 1; off < BKT_W; off <<= 1) {
        int v = 0;
        if (t < BKT_W && t >= off) v = ts[t - off];
        __syncthreads();
        if (t < BKT_W) ts[t] += v;
        __syncthreads();
    }
    if (t < BKT_W) {
        int exl = ts[t] - deg[t];
        cur[t] = exl;
        if (t < NL) row_off[nbase + t] = beg + exl;
    }
    __syncthreads();
    // placement: global csr_src (for agg2) + LDS copy (for the fused agg1)
    for (int k = beg + t; k < end; k += 512) {
        unsigned int pr = pairs[k];
        int dl = pr & (BKT_W - 1);
        int pos = atomicAdd(&cur[dl], 1);
        int src = (int)(pr >> 8);
        csr_src[beg + pos] = src;
        if (pos < SSRC_CAP) ssrc[pos] = (unsigned)src;
    }
    __syncthreads();

    // ---- fused agg1: 4 lanes per node, 128 node-groups, 2 passes ----
    const int wf32 = flags[2];
    int q = t & 3, grp = t >> 2;
    float b0, b1v, b2v, b3;
    if (wf32) {
        const float* b = (const float*)b1p + q * 4;
        b0 = b[0]; b1v = b[1]; b2v = b[2]; b3 = b[3];
    } else {
        const unsigned short* b = (const unsigned short*)b1p + q * 4;
        b0 = bf2f(b[0]); b1v = bf2f(b[1]); b2v = bf2f(b[2]); b3 = bf2f(b[3]);
    }
    for (int nl = grp; nl < NL; nl += 128) {
        int sL = ts[nl] - deg[nl];
        int eL = ts[nl];
        float a0 = 0.f, a1 = 0.f, a2 = 0.f, a3 = 0.f;
        int k = sL;
        for (; k + 8 <= eL; k += 8) {
            int sidx[8];
            uint2 v[8];
#pragma unroll
            for (int u = 0; u < 8; ++u)
                sidx[u] = (k + u < SSRC_CAP) ? (int)ssrc[k + u]
                                             : csr_src[beg + k + u];
#pragma unroll
            for (int u = 0; u < 8; ++u)
                v[u] = *(const uint2*)(m1 + (size_t)sidx[u] * HID + q * 4);
#pragma unroll
            for (int u = 0; u < 8; ++u) {
                a0 += bf2f((unsigned short)(v[u].x));
                a1 += bf2f((unsigned short)(v[u].x >> 16));
                a2 += bf2f((unsigned short)(v[u].y));
                a3 += bf2f((unsigned short)(v[u].y >> 16));
            }
        }
        for (; k < eL; ++k) {
            int s = (k < SSRC_CAP) ? (int)ssrc[k] : csr_src[beg + k];
            uint2 v = *(const uint2*)(m1 + (size_t)s * HID + q * 4);
            a0 += bf2f((unsigned short)(v.x));
            a1 += bf2f((unsigned short)(v.x >> 16));
            a2 += bf2f((unsigned short)(v.y));
            a3 += bf2f((unsigned short)(v.y >> 16));
        }
        float r0 = fmaxf(a0 + b0, 0.f);
        float r1 = fmaxf(a1 + b1v, 0.f);
        float r2 = fmaxf(a2 + b2v, 0.f);
        float r3 = fmaxf(a3 + b3, 0.f);
        uint2 packed;
        packed.x = (unsigned int)f2bf(r0) | ((unsigned int)f2bf(r1) << 16);
        packed.y = (unsigned int)f2bf(r2) | ((unsigned int)f2bf(r3) << 16);
        *(uint2*)(h + (size_t)(nbase + nl) * HID + q * 4) = packed;
    }
}

// ---------------- gather-sum core: 4 lanes/node, bf16 rows, 16-deep MLP -----
__device__ __forceinline__ v4f gather_bf16(const unsigned short* __restrict__ src,
                                           const int* __restrict__ csr_src,
                                           int beg, int end, int q) {
    float a0 = 0.f, a1 = 0.f, a2 = 0.f, a3 = 0.f;
    int k = beg;
    for (; k + 16 <= end; k += 16) {
        uint2 v[16];
#pragma unroll
        for (int u = 0; u < 16; ++u) {
            int s = csr_src[k + u];
            v[u] = *(const uint2*)(src + (size_t)s * HID + q * 4);
        }
#pragma unroll
        for (int u = 0; u < 16; ++u) {
            a0 += bf2f((unsigned short)(v[u].x));
            a1 += bf2f((unsigned short)(v[u].x >> 16));
            a2 += bf2f((unsigned short)(v[u].y));
            a3 += bf2f((unsigned short)(v[u].y >> 16));
        }
    }
    for (; k + 4 <= end; k += 4) {
        uint2 v[4];
#pragma unroll
        for (int u = 0; u < 4; ++u) {
            int s = csr_src[k + u];
            v[u] = *(const uint2*)(src + (size_t)s * HID + q * 4);
        }
#pragma unroll
        for (int u = 0; u < 4; ++u) {
            a0 += bf2f((unsigned short)(v[u].x));
            a1 += bf2f((unsigned short)(v[u].x >> 16));
            a2 += bf2f((unsigned short)(v[u].y));
            a3 += bf2f((unsigned short)(v[u].y >> 16));
        }
    }
    for (; k < end; ++k) {
        int s = csr_src[k];
        uint2 v = *(const uint2*)(src + (size_t)s * HID + q * 4);
        a0 += bf2f((unsigned short)(v.x));
        a1 += bf2f((unsigned short)(v.x >> 16));
        a2 += bf2f((unsigned short)(v.y));
        a3 += bf2f((unsigned short)(v.y >> 16));
    }
    v4f r = {a0, a1, a2, a3};
    return r;
}

// ---------------- agg2 + out fused: out = (A . h) @ W2 + b2 -----------------
__global__ void agg2_out_kernel(const unsigned short* __restrict__ h,
                                const int* __restrict__ row_off,
                                const int* __restrict__ csr_src,
                                const void* __restrict__ W2p,
                                const void* __restrict__ b2p,
                                void* __restrict__ out, int n_nodes,
                                const int* __restrict__ flags) {
    __shared__ float Ws[HID * OUTD];
    __shared__ float bs[OUTD];
    const int xf32 = flags[1], wf32 = flags[2];
    if (threadIdx.x < HID * OUTD)
        Ws[threadIdx.x] = wf32 ? ((const float*)W2p)[threadIdx.x]
                               : bf2f(((const unsigned short*)W2p)[threadIdx.x]);
    if (threadIdx.x < OUTD)
        bs[threadIdx.x] = wf32 ? ((const float*)b2p)[threadIdx.x]
                               : bf2f(((const unsigned short*)b2p)[threadIdx.x]);
    __syncthreads();

    int t = blockIdx.x * blockDim.x + threadIdx.x;
    int node = t >> 2;
    if (node >= n_nodes) return;
    int q = t & 3;
    v4f a = gather_bf16(h, csr_src, row_off[node], row_off[node + 1], q);

    float o[OUTD];
#pragma unroll
    for (int od = 0; od < OUTD; ++od) {
        float s = 0.f;
#pragma unroll
        for (int j = 0; j < 4; ++j)
            s = fmaf(a[j], Ws[(q * 4 + j) * OUTD + od], s);
        o[od] = s;
    }
#pragma unroll
    for (int od = 0; od < OUTD; ++od) {
        o[od] += __shfl_xor(o[od], 1);
        o[od] += __shfl_xor(o[od], 2);
        o[od] += bs[od];
    }

    if (xf32) {
        float2* po = (float2*)((float*)out + (size_t)node * OUTD);
        if (q == 0) {
            po[0] = make_float2(o[0], o[1]);
            po[1] = make_float2(o[2], o[3]);
        } else if (q == 1) {
            po[2] = make_float2(o[4], o[5]);
            po[3] = make_float2(o[6], o[7]);
        } else if (q == 2) {
            po[4] = make_float2(o[8], o[9]);
        }
    } else {
        unsigned int* po = (unsigned int*)((unsigned short*)out + (size_t)node * OUTD);
        if (q == 0) {
            po[0] = (unsigned int)f2bf(o[0]) | ((unsigned int)f2bf(o[1]) << 16);
            po[1] = (unsigned int)f2bf(o[2]) | ((unsigned int)f2bf(o[3]) << 16);
        } else if (q == 1) {
            po[2] = (unsigned int)f2bf(o[4]) | ((unsigned int)f2bf(o[5]) << 16);
            po[3] = (unsigned int)f2bf(o[6]) | ((unsigned int)f2bf(o[7]) << 16);
        } else if (q == 2) {
            po[4] = (unsigned int)f2bf(o[8]) | ((unsigned int)f2bf(o[9]) << 16);
        }
    }
}

// ---------------- Sentinel: ws_size too small -------------------------------
__global__ void sentinel_kernel(float* __restrict__ out) {
    if (blockIdx.x == 0 && threadIdx.x < 16) out[threadIdx.x] = 123456.0f;
}

extern "C" void kernel_launch(void* const* d_in, const int* in_sizes, int n_in,
                              void* d_out, int out_size, void* d_ws, size_t ws_size,
                              hipStream_t stream) {
    const void* x  = d_in[0];
    const void* ei = d_in[1];
    const void* W1 = d_in[2];
    const void* b1 = d_in[3];
    const void* W2 = d_in[4];
    const void* b2 = d_in[5];

    const int n_nodes = in_sizes[0] / IN_DIM;        // 100000
    const int n_edges = in_sizes[1] / 2;             // 3200000
    const int K = (n_nodes + BKT_W - 1) / BKT_W;     // 391 buckets

    // Workspace layout (256B-aligned). gemm1 overlaps part -> m1/h do not
    // alias pairs.
    char* p = (char*)d_ws;
    auto align = [](size_t v) { return (v + 255) & ~(size_t)255; };
    size_t off = 0;
    int* flags      = (int*)(p + off); off = align(off + 256);
    unsigned short* w1split = (unsigned short*)(p + off); off = align(off + 8192 * 2);
    int* bucket_cnt = (int*)(p + off); off = align(off + (size_t)K * 4);
    int* bucket_off = (int*)(p + off); off = align(off + ((size_t)K + 1) * 4);
    int* bcur       = (int*)(p + off); off = align(off + (size_t)K * 4);
    int* row_off    = (int*)(p + off); off = align(off + ((size_t)n_nodes + 1) * 4);
    int* csr_src    = (int*)(p + off); off = align(off + (size_t)n_edges * 4);
    unsigned int* pairs = (unsigned int*)(p + off); off = align(off + (size_t)n_edges * 4);
    unsigned short* m1 = (unsigned short*)(p + off); off = align(off + (size_t)n_nodes * HID * 2);
    unsigned short* h  = (unsigned short*)(p + off); off = align(off + (size_t)n_nodes * HID * 2);

    if (ws_size < off) {
        sentinel_kernel<<<1, 64, 0, stream>>>((float*)d_out);
        return;
    }

    const int n_tiles16 = (n_nodes + 15) >> 4;        // 6250
    const int g_gemm = (n_tiles16 + 3) / 4;           // 1563 (1 tile/wave)
    const int g_part = (n_edges + PART_CH - 1) / PART_CH;  // 782

    // 0. zero bucket counters (plain kernel; no memset API in capture path)
    zero_kernel<<<1, 256, 0, stream>>>(bucket_cnt, K);

    // 1. K1 fat: flags + W1 split + bucket histogram
    setup_bhist_kernel<<<17 + G_HIST, 256, 0, stream>>>(
        x, W1, ei, n_nodes, n_edges, flags, bucket_cnt, K, w1split);

    // 2. bucket scan
    bscan_kernel<<<1, 256, 0, stream>>>(bucket_cnt, K, bucket_off, bcur,
                                        row_off, n_nodes, n_edges);

    // 3. K2 fat: partition (bucket-sorted pairs) overlapped with gemm1 (m1)
    part_gemm1_kernel<<<g_part + g_gemm, 256, 0, stream>>>(
        ei, n_edges, bcur, pairs, x, w1split, m1, n_nodes, flags, K, g_part);

    // 4. K3: per-bucket CSR build + layer-1 aggregation fused
    csr_agg1_kernel<<<K, 512, 0, stream>>>(pairs, bucket_off, m1, b1,
                                           row_off, csr_src, h, n_nodes, flags);

    // 5. layer 2 aggregation + output GEMM fused
    {
        long long threads = (long long)n_nodes * 4;
        agg2_out_kernel<<<(int)((threads + 255) / 256), 256, 0, stream>>>(
            h, row_off, csr_src, W2, b2, d_out, n_nodes, flags);
    }
}